// Round 6
// baseline (395.930 us; speedup 1.0000x reference)
//
#include <hip/hip_runtime.h>
#include <math.h>

#define NEG_SLOPE 0.2f
#define LN_EPS 1e-5f

typedef __attribute__((ext_vector_type(2))) float f32x2;

// DPP-based add: x += x permuted by CTRL (within 16-lane rows)
template <int CTRL>
__device__ __forceinline__ float dpp_add(float x) {
    int s = __builtin_amdgcn_update_dpp(0, __float_as_int(x), CTRL, 0xF, 0xF, true);
    return x + __int_as_float(s);
}
// full 16-lane row sum
__device__ __forceinline__ float row16_sum(float x) {
    x = dpp_add<0xB1>(x);   // quad_perm [1,0,3,2]
    x = dpp_add<0x4E>(x);   // quad_perm [2,3,0,1]
    x = dpp_add<0x124>(x);  // row_ror:4
    x = dpp_add<0x128>(x);  // row_ror:8
    return x;
}

// ---------- prep: node transforms (xl,xr,xres) + dst histogram ----------
// 16 rows per block iteration, 4 rows per wave
__global__ __launch_bounds__(256) void prep(
    const float* __restrict__ x,
    const float* __restrict__ W_l, const float* __restrict__ b_l,
    const float* __restrict__ W_r, const float* __restrict__ b_r,
    const float* __restrict__ W_res, const float* __restrict__ b_res,
    float* __restrict__ xl, float* __restrict__ xr, float* __restrict__ xres,
    const int* __restrict__ ei, int* __restrict__ counts, int n, int E_) {
    __shared__ float sWl[4096];
    __shared__ float sWr[4096];
    __shared__ float sWs[4096];
    __shared__ float sx[16 * 64];
    for (int i = threadIdx.x; i < 4096; i += 256) {
        sWl[i] = W_l[i]; sWr[i] = W_r[i]; sWs[i] = W_res[i];
    }
    __syncthreads();
    int lane = threadIdx.x & 63;
    int w = threadIdx.x >> 6;
    float bl = b_l[lane], br = b_r[lane], bs = b_res[lane];
    for (int base = blockIdx.x * 16; base < n; base += gridDim.x * 16) {
        __syncthreads();
#pragma unroll
        for (int j = 0; j < 4; ++j) {
            int idx = threadIdx.x + j * 256;
            int row = base + (idx >> 6);
            row = row < n ? row : n - 1;
            sx[idx] = x[(size_t)row * 64 + (idx & 63)];
        }
        __syncthreads();
        float al[4], ar[4], as_[4];
#pragma unroll
        for (int j = 0; j < 4; ++j) { al[j] = bl; ar[j] = br; as_[j] = bs; }
        const float* x0 = &sx[(w * 4 + 0) * 64];
        const float* x1 = &sx[(w * 4 + 1) * 64];
        const float* x2 = &sx[(w * 4 + 2) * 64];
        const float* x3 = &sx[(w * 4 + 3) * 64];
#pragma unroll
        for (int k4 = 0; k4 < 16; ++k4) {
            float4 v0 = *(const float4*)&x0[k4 * 4];
            float4 v1 = *(const float4*)&x1[k4 * 4];
            float4 v2 = *(const float4*)&x2[k4 * 4];
            float4 v3 = *(const float4*)&x3[k4 * 4];
            float xv0[4] = {v0.x, v0.y, v0.z, v0.w};
            float xv1[4] = {v1.x, v1.y, v1.z, v1.w};
            float xv2[4] = {v2.x, v2.y, v2.z, v2.w};
            float xv3[4] = {v3.x, v3.y, v3.z, v3.w};
#pragma unroll
            for (int j = 0; j < 4; ++j) {
                int k = k4 * 4 + j;
                float wl = sWl[k * 64 + lane];
                float wr_ = sWr[k * 64 + lane];
                float ws_ = sWs[k * 64 + lane];
                al[0] = fmaf(xv0[j], wl, al[0]); ar[0] = fmaf(xv0[j], wr_, ar[0]); as_[0] = fmaf(xv0[j], ws_, as_[0]);
                al[1] = fmaf(xv1[j], wl, al[1]); ar[1] = fmaf(xv1[j], wr_, ar[1]); as_[1] = fmaf(xv1[j], ws_, as_[1]);
                al[2] = fmaf(xv2[j], wl, al[2]); ar[2] = fmaf(xv2[j], wr_, ar[2]); as_[2] = fmaf(xv2[j], ws_, as_[2]);
                al[3] = fmaf(xv3[j], wl, al[3]); ar[3] = fmaf(xv3[j], wr_, ar[3]); as_[3] = fmaf(xv3[j], ws_, as_[3]);
            }
        }
#pragma unroll
        for (int j = 0; j < 4; ++j) {
            int r = base + w * 4 + j;
            if (r < n) {
                xl[(size_t)r * 64 + lane] = al[j];
                xr[(size_t)r * 64 + lane] = ar[j];
                xres[(size_t)r * 64 + lane] = as_[j];
            }
        }
    }
    // histogram phase
    const int* di = ei + E_;
    for (int e = blockIdx.x * 256 + threadIdx.x; e < E_; e += gridDim.x * 256)
        atomicAdd(&counts[di[e]], 1);
}

// ---------- exclusive scan of counts -> starts (chunked) ----------
#define SCAN_CHUNK 1024
__global__ __launch_bounds__(256) void scan1(const int* __restrict__ counts,
                                             int* __restrict__ starts,
                                             int* __restrict__ partials, int n) {
    __shared__ int wsum[4];
    int base = blockIdx.x * SCAN_CHUNK;
    int t = threadIdx.x;
    int v[4]; int s = 0;
#pragma unroll
    for (int k = 0; k < 4; ++k) {
        int i = base + t * 4 + k;
        v[k] = (i < n) ? counts[i] : 0;
        s += v[k];
    }
    int lane = t & 63, w = t >> 6;
    int inc = s;
#pragma unroll
    for (int off = 1; off < 64; off <<= 1) {
        int u = __shfl_up(inc, off, 64);
        if (lane >= off) inc += u;
    }
    if (lane == 63) wsum[w] = inc;
    __syncthreads();
    int woff = 0;
    for (int i = 0; i < w; ++i) woff += wsum[i];
    int exc = woff + inc - s;
#pragma unroll
    for (int k = 0; k < 4; ++k) {
        int i = base + t * 4 + k;
        if (i < n) starts[i] = exc;
        exc += v[k];
    }
    if (t == 255) partials[blockIdx.x] = woff + inc;
}

__global__ __launch_bounds__(1024) void scan2(int* __restrict__ partials, int nchunks) {
    __shared__ int wsum[16];
    int t = threadIdx.x;
    int v = (t < nchunks) ? partials[t] : 0;
    int lane = t & 63, w = t >> 6;
    int inc = v;
#pragma unroll
    for (int off = 1; off < 64; off <<= 1) {
        int u = __shfl_up(inc, off, 64);
        if (lane >= off) inc += u;
    }
    if (lane == 63) wsum[w] = inc;
    __syncthreads();
    int woff = 0;
    for (int i = 0; i < w; ++i) woff += wsum[i];
    if (t < nchunks) partials[t] = woff + inc - v;
}

__global__ void scan3(int* __restrict__ starts, const int* __restrict__ partials, int n) {
    int i = blockIdx.x * blockDim.x + threadIdx.x;
    if (i < n) starts[i] += partials[i >> 10];
}

// ---------- place: es[starts[dst] + cursor[dst]++] = (e, src) ----------
__global__ void place_kernel(const int* __restrict__ ei, const int* __restrict__ starts,
                             int* __restrict__ cursor, int2* __restrict__ es, int E_) {
    int e = blockIdx.x * blockDim.x + threadIdx.x;
    if (e < E_) {
        int dst = ei[E_ + e];
        int idx = starts[dst] + atomicAdd(&cursor[dst], 1);
        es[idx] = make_int2(e, ei[e]);
    }
}

// ---------- fused: edge logits + deferred-max online softmax + gather + LN + res ------
// per-edge step: prefetch next eattr (uniform s_load) and next-next es/xl; compute cur
#define STEP(GCUR, GNEXT, I)                                                          \
    {                                                                                 \
        const float* pN = eattr + (size_t)__builtin_amdgcn_readfirstlane(eB.x) * 16;  \
        _Pragma("unroll") for (int k = 0; k < 8; ++k)                                 \
            GNEXT[k] = *(const f32x2*)(pN + 2 * k);                                   \
        f32x2 mm; mm.x = xA + base; mm.y = 0.0f;                                      \
        _Pragma("unroll") for (int k = 0; k < 8; ++k)                                 \
            mm = __builtin_elementwise_fma(GCUR[k], w2[k], mm);                       \
        float m = mm.x + mm.y;                                                        \
        m = fmaxf(m, NEG_SLOPE * m);                                                  \
        float l = row16_sum(m * attv);                                                \
        float d = l - mref;                                                           \
        if (__any(d > 8.0f)) {                                                        \
            float mnew = fmaxf(mref, l);                                              \
            float corr = __expf(mref - mnew);                                         \
            den *= corr; acc *= corr; mref = mnew; d = l - mref;                      \
        }                                                                             \
        float ex = __expf(d);                                                         \
        den += ex;                                                                    \
        acc = fmaf(ex, xA, acc);                                                      \
        xA = xB; xB = xl[((unsigned)eC.y << 6) | lane];                               \
        eB = eC;                                                                      \
        int nx = s0 + (I) + 3; nx = nx > last ? last : nx;                            \
        eC = es[nx];                                                                  \
    }

__global__ __launch_bounds__(256) void fused_gather(
    const int* __restrict__ starts, const int* __restrict__ counts,
    const int2* __restrict__ es, const float* __restrict__ eattr,
    const int* __restrict__ dist, const float* __restrict__ bph,
    const float* __restrict__ W_e, const float* __restrict__ att,
    const float* __restrict__ xl, const float* __restrict__ xr,
    const float* __restrict__ xres, const float* __restrict__ bias,
    const float* __restrict__ gamma, const float* __restrict__ beta,
    float* __restrict__ out, int n) {
    int lane = threadIdx.x & 63;
    float attv = att[lane];
    float bi = bias[lane], g = gamma[lane], be = beta[lane];
    f32x2 w2[8];
    float wsum = 0.0f;
#pragma unroll
    for (int k = 0; k < 8; ++k) {
        w2[k].x = W_e[(2 * k) * 64 + lane];
        w2[k].y = W_e[(2 * k + 1) * 64 + lane];
        wsum += w2[k].x + w2[k].y;
    }

    int wid = (blockIdx.x * blockDim.x + threadIdx.x) >> 6;
    int nw = (gridDim.x * blockDim.x) >> 6;
    for (int r = wid; r < n; r += nw) {
        int s0 = starts[r];
        int cnt = counts[r];
        float mref = 0.0f, den = 0.0f, acc = 0.0f;
        if (cnt > 0) {
            int hop = dist[r];
            hop = hop < 0 ? 0 : (hop > 3 ? 3 : hop);
            float hb = 0.1f * bph[hop];
            float base = fmaf(hb, wsum, xr[((unsigned)r << 6) | lane]);
            int last = s0 + cnt - 1;
            int iB = s0 + 1 > last ? last : s0 + 1;
            int iC = s0 + 2 > last ? last : s0 + 2;
            int2 e0 = es[s0];
            int2 eB = es[iB];
            int2 eC = es[iC];
            float xA = xl[((unsigned)e0.y << 6) | lane];
            float xB = xl[((unsigned)eB.y << 6) | lane];
            f32x2 g0[8], g1[8];
            {
                const float* p = eattr + (size_t)__builtin_amdgcn_readfirstlane(e0.x) * 16;
#pragma unroll
                for (int k = 0; k < 8; ++k) g0[k] = *(const f32x2*)(p + 2 * k);
            }
            int i = 0;
            for (;;) {
                STEP(g0, g1, i);
                if (++i >= cnt) break;
                STEP(g1, g0, i);
                if (++i >= cnt) break;
            }
        }
        float v = acc / (den + 1e-16f) + bi;
        // LayerNorm over 64 features (row16 DPP + 2 cross-row shuffles)
        float s = row16_sum(v);
        s += __shfl_xor(s, 16, 64);
        s += __shfl_xor(s, 32, 64);
        float mu = s * (1.0f / 64.0f);
        float dd = v - mu;
        float q = row16_sum(dd * dd);
        q += __shfl_xor(q, 16, 64);
        q += __shfl_xor(q, 32, 64);
        float var = q * (1.0f / 64.0f);
        float nv = dd * rsqrtf(var + LN_EPS) * g + be;
        out[((unsigned)r << 6) | lane] = nv + xres[((unsigned)r << 6) | lane];
    }
}

extern "C" void kernel_launch(void* const* d_in, const int* in_sizes, int n_in,
                              void* d_out, int out_size, void* d_ws, size_t ws_size,
                              hipStream_t stream) {
    const float* x     = (const float*)d_in[0];
    const int*   ei    = (const int*)d_in[1];
    const float* eattr = (const float*)d_in[2];
    const int*   dist  = (const int*)d_in[3];
    const float* W_l   = (const float*)d_in[4];
    const float* b_l   = (const float*)d_in[5];
    const float* W_r   = (const float*)d_in[6];
    const float* b_r   = (const float*)d_in[7];
    const float* W_e   = (const float*)d_in[8];
    const float* att   = (const float*)d_in[9];
    const float* bias  = (const float*)d_in[10];
    const float* gamma = (const float*)d_in[11];
    const float* beta  = (const float*)d_in[12];
    const float* W_res = (const float*)d_in[13];
    const float* b_res = (const float*)d_in[14];
    const float* bph   = (const float*)d_in[15];

    int n  = in_sizes[0] / 64;
    int E_ = in_sizes[1] / 2;
    float* out = (float*)d_out;

    char* ws = (char*)d_ws;
    float* xl       = (float*)ws; ws += (size_t)n * 64 * 4;
    float* xr       = (float*)ws; ws += (size_t)n * 64 * 4;
    float* xres     = (float*)ws; ws += (size_t)n * 64 * 4;
    int2*  es       = (int2*)ws;  ws += (size_t)E_ * 8;
    int*   counts   = (int*)ws;   ws += (size_t)n * 4;
    int*   cursor   = (int*)ws;   ws += (size_t)n * 4;
    int*   starts   = (int*)ws;   ws += (size_t)n * 4;
    int*   partials = (int*)ws;   ws += (size_t)1024 * 4;

    int nchunks = (n + SCAN_CHUNK - 1) / SCAN_CHUNK;

    hipMemsetAsync(counts, 0, (size_t)n * 2 * 4, stream);  // counts + cursor
    prep<<<2048, 256, 0, stream>>>(x, W_l, b_l, W_r, b_r, W_res, b_res,
                                   xl, xr, xres, ei, counts, n, E_);
    scan1<<<nchunks, 256, 0, stream>>>(counts, starts, partials, n);
    scan2<<<1, 1024, 0, stream>>>(partials, nchunks);
    scan3<<<(n + 255) / 256, 256, 0, stream>>>(starts, partials, n);
    place_kernel<<<(E_ + 255) / 256, 256, 0, stream>>>(ei, starts, cursor, es, E_);
    fused_gather<<<2048, 256, 0, stream>>>(starts, counts, es, eattr, dist, bph,
                                           W_e, att, xl, xr, xres,
                                           bias, gamma, beta, out, n);
}

// Round 7
// 394.186 us; speedup vs baseline: 1.0044x; 1.0044x over previous
//
#include <hip/hip_runtime.h>
#include <math.h>

#define NEG_SLOPE 0.2f
#define LN_EPS 1e-5f

typedef __attribute__((ext_vector_type(2))) float f32x2;

// DPP-based add: x += x permuted by CTRL (within 16-lane rows)
template <int CTRL>
__device__ __forceinline__ float dpp_add(float x) {
    int s = __builtin_amdgcn_update_dpp(0, __float_as_int(x), CTRL, 0xF, 0xF, true);
    return x + __int_as_float(s);
}
// full 16-lane row sum
__device__ __forceinline__ float row16_sum(float x) {
    x = dpp_add<0xB1>(x);   // quad_perm [1,0,3,2]
    x = dpp_add<0x4E>(x);   // quad_perm [2,3,0,1]
    x = dpp_add<0x124>(x);  // row_ror:4
    x = dpp_add<0x128>(x);  // row_ror:8
    return x;
}

// ---------- prep: node transforms (xl,xr,xres) + dst histogram (round-4 form) --------
__global__ __launch_bounds__(256) void prep(
    const float* __restrict__ x,
    const float* __restrict__ W_l, const float* __restrict__ b_l,
    const float* __restrict__ W_r, const float* __restrict__ b_r,
    const float* __restrict__ W_res, const float* __restrict__ b_res,
    float* __restrict__ xl, float* __restrict__ xr, float* __restrict__ xres,
    const int* __restrict__ ei, int* __restrict__ counts, int n, int E_) {
    __shared__ float sWl[4096];
    __shared__ float sWr[4096];
    __shared__ float sWs[4096];
    __shared__ float sx[256];
    for (int i = threadIdx.x; i < 4096; i += 256) {
        sWl[i] = W_l[i]; sWr[i] = W_r[i]; sWs[i] = W_res[i];
    }
    __syncthreads();
    int lane = threadIdx.x & 63;
    int w = threadIdx.x >> 6;
    float bl = b_l[lane], br = b_r[lane], bs = b_res[lane];
    for (int base = blockIdx.x * 4; base < n; base += gridDim.x * 4) {
        __syncthreads();
        int r = base + w;
        if (r < n) sx[threadIdx.x] = x[(size_t)r * 64 + lane];
        __syncthreads();
        if (r < n) {
            float al = bl, ar = br, as_ = bs;
            const float* xv = &sx[w * 64];
#pragma unroll
            for (int k = 0; k < 64; ++k) {
                float xk = xv[k];
                al = fmaf(xk, sWl[k * 64 + lane], al);
                ar = fmaf(xk, sWr[k * 64 + lane], ar);
                as_ = fmaf(xk, sWs[k * 64 + lane], as_);
            }
            xl[(size_t)r * 64 + lane] = al;
            xr[(size_t)r * 64 + lane] = ar;
            xres[(size_t)r * 64 + lane] = as_;
        }
    }
    // histogram phase
    const int* di = ei + E_;
    for (int e = blockIdx.x * 256 + threadIdx.x; e < E_; e += gridDim.x * 256)
        atomicAdd(&counts[di[e]], 1);
}

// ---------- exclusive scan of counts -> starts (chunked) ----------
#define SCAN_CHUNK 1024
__global__ __launch_bounds__(256) void scan1(const int* __restrict__ counts,
                                             int* __restrict__ starts,
                                             int* __restrict__ partials, int n) {
    __shared__ int wsum[4];
    int base = blockIdx.x * SCAN_CHUNK;
    int t = threadIdx.x;
    int v[4]; int s = 0;
#pragma unroll
    for (int k = 0; k < 4; ++k) {
        int i = base + t * 4 + k;
        v[k] = (i < n) ? counts[i] : 0;
        s += v[k];
    }
    int lane = t & 63, w = t >> 6;
    int inc = s;
#pragma unroll
    for (int off = 1; off < 64; off <<= 1) {
        int u = __shfl_up(inc, off, 64);
        if (lane >= off) inc += u;
    }
    if (lane == 63) wsum[w] = inc;
    __syncthreads();
    int woff = 0;
    for (int i = 0; i < w; ++i) woff += wsum[i];
    int exc = woff + inc - s;
#pragma unroll
    for (int k = 0; k < 4; ++k) {
        int i = base + t * 4 + k;
        if (i < n) starts[i] = exc;
        exc += v[k];
    }
    if (t == 255) partials[blockIdx.x] = woff + inc;
}

__global__ __launch_bounds__(1024) void scan2(int* __restrict__ partials, int nchunks) {
    __shared__ int wsum[16];
    int t = threadIdx.x;
    int v = (t < nchunks) ? partials[t] : 0;
    int lane = t & 63, w = t >> 6;
    int inc = v;
#pragma unroll
    for (int off = 1; off < 64; off <<= 1) {
        int u = __shfl_up(inc, off, 64);
        if (lane >= off) inc += u;
    }
    if (lane == 63) wsum[w] = inc;
    __syncthreads();
    int woff = 0;
    for (int i = 0; i < w; ++i) woff += wsum[i];
    if (t < nchunks) partials[t] = woff + inc - v;
}

__global__ void scan3(int* __restrict__ starts, const int* __restrict__ partials, int n) {
    int i = blockIdx.x * blockDim.x + threadIdx.x;
    if (i < n) starts[i] += partials[i >> 10];
}

// ---------- place: es[starts[dst] + cursor[dst]++] = (e, src) ----------
__global__ void place_kernel(const int* __restrict__ ei, const int* __restrict__ starts,
                             int* __restrict__ cursor, int2* __restrict__ es, int E_) {
    int e = blockIdx.x * blockDim.x + threadIdx.x;
    if (e < E_) {
        int dst = ei[E_ + e];
        int idx = starts[dst] + atomicAdd(&cursor[dst], 1);
        es[idx] = make_int2(e, ei[e]);
    }
}

// ---------- fused: TWO nodes per wave, dual independent pipelines ----------
#define STEP_S(S, GCUR, GNEXT, I)                                                     \
    {                                                                                 \
        const float* pN = eattr + (size_t)__builtin_amdgcn_readfirstlane(eB##S.x) * 16; \
        _Pragma("unroll") for (int k = 0; k < 8; ++k)                                 \
            GNEXT[k] = *(const f32x2*)(pN + 2 * k);                                   \
        f32x2 mm; mm.x = xA##S + base##S; mm.y = 0.0f;                                \
        _Pragma("unroll") for (int k = 0; k < 8; ++k)                                 \
            mm = __builtin_elementwise_fma(GCUR[k], w2[k], mm);                       \
        float m = mm.x + mm.y;                                                        \
        m = fmaxf(m, NEG_SLOPE * m);                                                  \
        float l = row16_sum(m * attv);                                                \
        l = (I) < cnt##S ? l : -1e30f;                                                \
        float d = l - mref##S;                                                        \
        if (__any(d > 8.0f)) {                                                        \
            float mnew = fmaxf(mref##S, l);                                           \
            float corr = __expf(mref##S - mnew);                                      \
            den##S *= corr; acc##S *= corr; mref##S = mnew; d = l - mref##S;          \
        }                                                                             \
        float ex = __expf(d);                                                         \
        den##S += ex;                                                                 \
        acc##S = fmaf(ex, xA##S, acc##S);                                             \
        xA##S = xB##S; xB##S = xl[((unsigned)eC##S.y << 6) | lane];                   \
        eB##S = eC##S;                                                                \
        int nx = s0##S + (I) + 3; nx = nx > last##S ? last##S : nx;                   \
        eC##S = es[nx];                                                               \
    }

#define INIT_S(S, R)                                                                  \
    int rc##S = (R) < n ? (R) : n - 1;                                                \
    int s0##S = starts[rc##S];                                                        \
    int cnt##S = (R) < n ? counts[rc##S] : 0;                                         \
    int sc##S = s0##S < E_ - 1 ? s0##S : E_ - 1;                                      \
    int last##S = cnt##S > 0 ? s0##S + cnt##S - 1 : sc##S;                            \
    float mref##S = 0.0f, den##S = 0.0f, acc##S = 0.0f;                               \
    float base##S;                                                                    \
    {                                                                                 \
        int hop = dist[rc##S];                                                        \
        hop = hop < 0 ? 0 : (hop > 3 ? 3 : hop);                                      \
        base##S = fmaf(0.1f * bph[hop], wsum, xr[((unsigned)rc##S << 6) | lane]);     \
    }                                                                                 \
    int iB##S = sc##S + 1 > last##S ? last##S : sc##S + 1;                            \
    int iC##S = sc##S + 2 > last##S ? last##S : sc##S + 2;                            \
    int2 e0##S = es[sc##S];                                                           \
    int2 eB##S = es[iB##S];                                                           \
    int2 eC##S = es[iC##S];                                                           \
    float xA##S = xl[((unsigned)e0##S.y << 6) | lane];                                \
    float xB##S = xl[((unsigned)eB##S.y << 6) | lane];                                \
    f32x2 g0##S[8], g1##S[8];                                                         \
    {                                                                                 \
        const float* p = eattr + (size_t)__builtin_amdgcn_readfirstlane(e0##S.x) * 16; \
        _Pragma("unroll") for (int k = 0; k < 8; ++k) g0##S[k] = *(const f32x2*)(p + 2 * k); \
    }

#define EPILOGUE_S(S, R)                                                              \
    if ((R) < n) {                                                                    \
        float v = acc##S / (den##S + 1e-16f) + bi;                                    \
        float s = row16_sum(v);                                                       \
        s += __shfl_xor(s, 16, 64);                                                   \
        s += __shfl_xor(s, 32, 64);                                                   \
        float mu = s * (1.0f / 64.0f);                                                \
        float dd = v - mu;                                                            \
        float q = row16_sum(dd * dd);                                                 \
        q += __shfl_xor(q, 16, 64);                                                   \
        q += __shfl_xor(q, 32, 64);                                                   \
        float var = q * (1.0f / 64.0f);                                               \
        float nv = dd * rsqrtf(var + LN_EPS) * g + be;                                \
        out[((unsigned)(R) << 6) | lane] = nv + xres[((unsigned)(R) << 6) | lane];    \
    }

__global__ __launch_bounds__(256) void fused_gather(
    const int* __restrict__ starts, const int* __restrict__ counts,
    const int2* __restrict__ es, const float* __restrict__ eattr,
    const int* __restrict__ dist, const float* __restrict__ bph,
    const float* __restrict__ W_e, const float* __restrict__ att,
    const float* __restrict__ xl, const float* __restrict__ xr,
    const float* __restrict__ xres, const float* __restrict__ bias,
    const float* __restrict__ gamma, const float* __restrict__ beta,
    float* __restrict__ out, int n, int E_) {
    int lane = threadIdx.x & 63;
    float attv = att[lane];
    float bi = bias[lane], g = gamma[lane], be = beta[lane];
    f32x2 w2[8];
    float wsum = 0.0f;
#pragma unroll
    for (int k = 0; k < 8; ++k) {
        w2[k].x = W_e[(2 * k) * 64 + lane];
        w2[k].y = W_e[(2 * k + 1) * 64 + lane];
        wsum += w2[k].x + w2[k].y;
    }

    int wid = (blockIdx.x * blockDim.x + threadIdx.x) >> 6;
    int nw = (gridDim.x * blockDim.x) >> 6;
    int npairs = (n + 1) >> 1;
    for (int p = wid; p < npairs; p += nw) {
        int r0 = p * 2;
        int r1 = r0 + 1;
        INIT_S(0, r0)
        INIT_S(1, r1)
        int mx = cnt0 > cnt1 ? cnt0 : cnt1;
        int i = 0;
        if (mx > 0) {
            for (;;) {
                STEP_S(0, g00, g10, i)
                STEP_S(1, g01, g11, i)
                if (++i >= mx) break;
                STEP_S(0, g10, g00, i)
                STEP_S(1, g11, g01, i)
                if (++i >= mx) break;
            }
        }
        EPILOGUE_S(0, r0)
        EPILOGUE_S(1, r1)
    }
}

extern "C" void kernel_launch(void* const* d_in, const int* in_sizes, int n_in,
                              void* d_out, int out_size, void* d_ws, size_t ws_size,
                              hipStream_t stream) {
    const float* x     = (const float*)d_in[0];
    const int*   ei    = (const int*)d_in[1];
    const float* eattr = (const float*)d_in[2];
    const int*   dist  = (const int*)d_in[3];
    const float* W_l   = (const float*)d_in[4];
    const float* b_l   = (const float*)d_in[5];
    const float* W_r   = (const float*)d_in[6];
    const float* b_r   = (const float*)d_in[7];
    const float* W_e   = (const float*)d_in[8];
    const float* att   = (const float*)d_in[9];
    const float* bias  = (const float*)d_in[10];
    const float* gamma = (const float*)d_in[11];
    const float* beta  = (const float*)d_in[12];
    const float* W_res = (const float*)d_in[13];
    const float* b_res = (const float*)d_in[14];
    const float* bph   = (const float*)d_in[15];

    int n  = in_sizes[0] / 64;
    int E_ = in_sizes[1] / 2;
    float* out = (float*)d_out;

    char* ws = (char*)d_ws;
    float* xl       = (float*)ws; ws += (size_t)n * 64 * 4;
    float* xr       = (float*)ws; ws += (size_t)n * 64 * 4;
    float* xres     = (float*)ws; ws += (size_t)n * 64 * 4;
    int2*  es       = (int2*)ws;  ws += (size_t)E_ * 8;
    int*   counts   = (int*)ws;   ws += (size_t)n * 4;
    int*   cursor   = (int*)ws;   ws += (size_t)n * 4;
    int*   starts   = (int*)ws;   ws += (size_t)n * 4;
    int*   partials = (int*)ws;   ws += (size_t)1024 * 4;

    int nchunks = (n + SCAN_CHUNK - 1) / SCAN_CHUNK;

    hipMemsetAsync(counts, 0, (size_t)n * 2 * 4, stream);  // counts + cursor
    prep<<<2048, 256, 0, stream>>>(x, W_l, b_l, W_r, b_r, W_res, b_res,
                                   xl, xr, xres, ei, counts, n, E_);
    scan1<<<nchunks, 256, 0, stream>>>(counts, starts, partials, n);
    scan2<<<1, 1024, 0, stream>>>(partials, nchunks);
    scan3<<<(n + 255) / 256, 256, 0, stream>>>(starts, partials, n);
    place_kernel<<<(E_ + 255) / 256, 256, 0, stream>>>(ei, starts, cursor, es, E_);
    fused_gather<<<2048, 256, 0, stream>>>(starts, counts, es, eattr, dist, bph,
                                           W_e, att, xl, xr, xres,
                                           bias, gamma, beta, out, n, E_);
}

// Round 8
// 351.603 us; speedup vs baseline: 1.1261x; 1.1211x over previous
//
#include <hip/hip_runtime.h>
#include <math.h>

#define NEG_SLOPE 0.2f
#define LN_EPS 1e-5f

typedef __attribute__((ext_vector_type(2))) float f32x2;

// DPP-based add: x += x permuted by CTRL (within 16-lane rows)
template <int CTRL>
__device__ __forceinline__ float dpp_add(float x) {
    int s = __builtin_amdgcn_update_dpp(0, __float_as_int(x), CTRL, 0xF, 0xF, true);
    return x + __int_as_float(s);
}
// full 16-lane row sum
__device__ __forceinline__ float row16_sum(float x) {
    x = dpp_add<0xB1>(x);   // quad_perm [1,0,3,2]
    x = dpp_add<0x4E>(x);   // quad_perm [2,3,0,1]
    x = dpp_add<0x124>(x);  // row_ror:4
    x = dpp_add<0x128>(x);  // row_ror:8
    return x;
}

// ---------- prep: node transforms (xl,xr,xres) + dst histogram ----------
__global__ __launch_bounds__(256) void prep(
    const float* __restrict__ x,
    const float* __restrict__ W_l, const float* __restrict__ b_l,
    const float* __restrict__ W_r, const float* __restrict__ b_r,
    const float* __restrict__ W_res, const float* __restrict__ b_res,
    float* __restrict__ xl, float* __restrict__ xr, float* __restrict__ xres,
    const int* __restrict__ ei, int* __restrict__ counts, int n, int E_) {
    __shared__ float sWl[4096];
    __shared__ float sWr[4096];
    __shared__ float sWs[4096];
    __shared__ float sx[256];
    for (int i = threadIdx.x; i < 4096; i += 256) {
        sWl[i] = W_l[i]; sWr[i] = W_r[i]; sWs[i] = W_res[i];
    }
    __syncthreads();
    int lane = threadIdx.x & 63;
    int w = threadIdx.x >> 6;
    float bl = b_l[lane], br = b_r[lane], bs = b_res[lane];
    for (int base = blockIdx.x * 4; base < n; base += gridDim.x * 4) {
        __syncthreads();
        int r = base + w;
        if (r < n) sx[threadIdx.x] = x[(size_t)r * 64 + lane];
        __syncthreads();
        if (r < n) {
            float al = bl, ar = br, as_ = bs;
            const float* xv = &sx[w * 64];
#pragma unroll
            for (int k = 0; k < 64; ++k) {
                float xk = xv[k];
                al = fmaf(xk, sWl[k * 64 + lane], al);
                ar = fmaf(xk, sWr[k * 64 + lane], ar);
                as_ = fmaf(xk, sWs[k * 64 + lane], as_);
            }
            xl[(size_t)r * 64 + lane] = al;
            xr[(size_t)r * 64 + lane] = ar;
            xres[(size_t)r * 64 + lane] = as_;
        }
    }
    // histogram phase
    const int* di = ei + E_;
    for (int e = blockIdx.x * 256 + threadIdx.x; e < E_; e += gridDim.x * 256)
        atomicAdd(&counts[di[e]], 1);
}

// ---------- exclusive scan of counts -> starts (chunked) ----------
#define SCAN_CHUNK 1024
__global__ __launch_bounds__(256) void scan1(const int* __restrict__ counts,
                                             int* __restrict__ starts,
                                             int* __restrict__ partials, int n) {
    __shared__ int wsum[4];
    int base = blockIdx.x * SCAN_CHUNK;
    int t = threadIdx.x;
    int v[4]; int s = 0;
#pragma unroll
    for (int k = 0; k < 4; ++k) {
        int i = base + t * 4 + k;
        v[k] = (i < n) ? counts[i] : 0;
        s += v[k];
    }
    int lane = t & 63, w = t >> 6;
    int inc = s;
#pragma unroll
    for (int off = 1; off < 64; off <<= 1) {
        int u = __shfl_up(inc, off, 64);
        if (lane >= off) inc += u;
    }
    if (lane == 63) wsum[w] = inc;
    __syncthreads();
    int woff = 0;
    for (int i = 0; i < w; ++i) woff += wsum[i];
    int exc = woff + inc - s;
#pragma unroll
    for (int k = 0; k < 4; ++k) {
        int i = base + t * 4 + k;
        if (i < n) starts[i] = exc;
        exc += v[k];
    }
    if (t == 255) partials[blockIdx.x] = woff + inc;
}

__global__ __launch_bounds__(1024) void scan2(int* __restrict__ partials, int nchunks) {
    __shared__ int wsum[16];
    int t = threadIdx.x;
    int v = (t < nchunks) ? partials[t] : 0;
    int lane = t & 63, w = t >> 6;
    int inc = v;
#pragma unroll
    for (int off = 1; off < 64; off <<= 1) {
        int u = __shfl_up(inc, off, 64);
        if (lane >= off) inc += u;
    }
    if (lane == 63) wsum[w] = inc;
    __syncthreads();
    int woff = 0;
    for (int i = 0; i < w; ++i) woff += wsum[i];
    if (t < nchunks) partials[t] = woff + inc - v;
}

__global__ void scan3(int* __restrict__ starts, const int* __restrict__ partials, int n) {
    int i = blockIdx.x * blockDim.x + threadIdx.x;
    if (i < n) starts[i] += partials[i >> 10];
}

// ---------- place: es[starts[dst] + cursor[dst]++] = (e, src) ----------
__global__ void place_kernel(const int* __restrict__ ei, const int* __restrict__ starts,
                             int* __restrict__ cursor, int2* __restrict__ es, int E_) {
    int e = blockIdx.x * blockDim.x + threadIdx.x;
    if (e < E_) {
        int dst = ei[E_ + e];
        int idx = starts[dst] + atomicAdd(&cursor[dst], 1);
        es[idx] = make_int2(e, ei[e]);
    }
}

// ---------- fused gather: 3-phase rotating pipeline, depth-3 prefetch ----------
#define LOAD_G(G, EA)                                                       \
    {                                                                       \
        int ec = __builtin_amdgcn_readfirstlane((EA).x);                    \
        const f32x2* p = (const f32x2*)(eattr + (size_t)ec * 16);           \
        _Pragma("unroll") for (int k = 0; k < 8; ++k) G[k] = p[k];          \
    }

// consume edge I using (G,X); refill (G,X) for edge I+3 from E; refill E for edge I+6
#define PHASE(G, X, E, I)                                                   \
    {                                                                       \
        f32x2 mm; mm.x = X + base; mm.y = 0.0f;                             \
        _Pragma("unroll") for (int k = 0; k < 8; ++k)                       \
            mm = __builtin_elementwise_fma(G[k], w2[k], mm);                \
        float m = mm.x + mm.y;                                              \
        m = fmaxf(m, NEG_SLOPE * m);                                        \
        float l = row16_sum(m * attv);                                      \
        l = (I) < cnt ? l : -1e30f;                                         \
        float d = l - mref;                                                 \
        if (__any(d > 8.0f)) {                                              \
            float mnew = fmaxf(mref, l);                                    \
            float corr = __expf(mref - mnew);                               \
            den *= corr; acc *= corr; mref = mnew; d = l - mref;            \
        }                                                                   \
        float ex = __expf(d);                                               \
        den += ex;                                                          \
        acc = fmaf(ex, X, acc);                                             \
        X = xl[((unsigned)(E).y << 6) | lane];                              \
        LOAD_G(G, E);                                                       \
        int nx = s0 + (I) + 6; nx = nx > last ? last : nx;                  \
        E = es[nx];                                                         \
    }

__global__ __launch_bounds__(256) void fused_gather(
    const int* __restrict__ starts, const int* __restrict__ counts,
    const int2* __restrict__ es, const float* __restrict__ eattr,
    const int* __restrict__ dist, const float* __restrict__ bph,
    const float* __restrict__ W_e, const float* __restrict__ att,
    const float* __restrict__ xl, const float* __restrict__ xr,
    const float* __restrict__ xres, const float* __restrict__ bias,
    const float* __restrict__ gamma, const float* __restrict__ beta,
    float* __restrict__ out, int n) {
    int lane = threadIdx.x & 63;
    float attv = att[lane];
    float bi = bias[lane], g = gamma[lane], be = beta[lane];
    f32x2 w2[8];
    float wsum = 0.0f;
#pragma unroll
    for (int k = 0; k < 8; ++k) {
        w2[k].x = W_e[(2 * k) * 64 + lane];
        w2[k].y = W_e[(2 * k + 1) * 64 + lane];
        wsum += w2[k].x + w2[k].y;
    }

    int wid = (blockIdx.x * blockDim.x + threadIdx.x) >> 6;
    int nw = (gridDim.x * blockDim.x) >> 6;
    for (int r = wid; r < n; r += nw) {
        int s0 = starts[r];
        int cnt = counts[r];
        float mref = 0.0f, den = 0.0f, acc = 0.0f;
        if (cnt > 0) {
            int hop = dist[r];
            hop = hop < 0 ? 0 : (hop > 3 ? 3 : hop);
            float hb = 0.1f * bph[hop];
            float base = fmaf(hb, wsum, xr[((unsigned)r << 6) | lane]);
            int last = s0 + cnt - 1;
            int i1 = s0 + 1 > last ? last : s0 + 1;
            int i2 = s0 + 2 > last ? last : s0 + 2;
            int i3 = s0 + 3 > last ? last : s0 + 3;
            int i4 = s0 + 4 > last ? last : s0 + 4;
            int i5 = s0 + 5 > last ? last : s0 + 5;
            int2 A0 = es[s0];
            int2 A1 = es[i1];
            int2 A2 = es[i2];
            int2 E0 = es[i3];
            int2 E1 = es[i4];
            int2 E2 = es[i5];
            float X0 = xl[((unsigned)A0.y << 6) | lane];
            float X1 = xl[((unsigned)A1.y << 6) | lane];
            float X2 = xl[((unsigned)A2.y << 6) | lane];
            f32x2 G0[8], G1[8], G2[8];
            LOAD_G(G0, A0);
            LOAD_G(G1, A1);
            LOAD_G(G2, A2);
            for (int i = 0; i < cnt; i += 3) {
                PHASE(G0, X0, E0, i)
                PHASE(G1, X1, E1, i + 1)
                PHASE(G2, X2, E2, i + 2)
            }
        }
        float v = acc / (den + 1e-16f) + bi;
        // LayerNorm over 64 features
        float s = row16_sum(v);
        s += __shfl_xor(s, 16, 64);
        s += __shfl_xor(s, 32, 64);
        float mu = s * (1.0f / 64.0f);
        float dd = v - mu;
        float q = row16_sum(dd * dd);
        q += __shfl_xor(q, 16, 64);
        q += __shfl_xor(q, 32, 64);
        float var = q * (1.0f / 64.0f);
        float nv = dd * rsqrtf(var + LN_EPS) * g + be;
        out[((unsigned)r << 6) | lane] = nv + xres[((unsigned)r << 6) | lane];
    }
}

extern "C" void kernel_launch(void* const* d_in, const int* in_sizes, int n_in,
                              void* d_out, int out_size, void* d_ws, size_t ws_size,
                              hipStream_t stream) {
    const float* x     = (const float*)d_in[0];
    const int*   ei    = (const int*)d_in[1];
    const float* eattr = (const float*)d_in[2];
    const int*   dist  = (const int*)d_in[3];
    const float* W_l   = (const float*)d_in[4];
    const float* b_l   = (const float*)d_in[5];
    const float* W_r   = (const float*)d_in[6];
    const float* b_r   = (const float*)d_in[7];
    const float* W_e   = (const float*)d_in[8];
    const float* att   = (const float*)d_in[9];
    const float* bias  = (const float*)d_in[10];
    const float* gamma = (const float*)d_in[11];
    const float* beta  = (const float*)d_in[12];
    const float* W_res = (const float*)d_in[13];
    const float* b_res = (const float*)d_in[14];
    const float* bph   = (const float*)d_in[15];

    int n  = in_sizes[0] / 64;
    int E_ = in_sizes[1] / 2;
    float* out = (float*)d_out;

    char* ws = (char*)d_ws;
    float* xl       = (float*)ws; ws += (size_t)n * 64 * 4;
    float* xr       = (float*)ws; ws += (size_t)n * 64 * 4;
    float* xres     = (float*)ws; ws += (size_t)n * 64 * 4;
    int2*  es       = (int2*)ws;  ws += (size_t)E_ * 8;
    int*   counts   = (int*)ws;   ws += (size_t)n * 4;
    int*   cursor   = (int*)ws;   ws += (size_t)n * 4;
    int*   starts   = (int*)ws;   ws += (size_t)n * 4;
    int*   partials = (int*)ws;   ws += (size_t)1024 * 4;

    int nchunks = (n + SCAN_CHUNK - 1) / SCAN_CHUNK;

    hipMemsetAsync(counts, 0, (size_t)n * 2 * 4, stream);  // counts + cursor
    prep<<<2048, 256, 0, stream>>>(x, W_l, b_l, W_r, b_r, W_res, b_res,
                                   xl, xr, xres, ei, counts, n, E_);
    scan1<<<nchunks, 256, 0, stream>>>(counts, starts, partials, n);
    scan2<<<1, 1024, 0, stream>>>(partials, nchunks);
    scan3<<<(n + 255) / 256, 256, 0, stream>>>(starts, partials, n);
    place_kernel<<<(E_ + 255) / 256, 256, 0, stream>>>(ei, starts, cursor, es, E_);
    fused_gather<<<4096, 256, 0, stream>>>(starts, counts, es, eattr, dist, bph,
                                           W_e, att, xl, xr, xres,
                                           bias, gamma, beta, out, n);
}